// Round 8
// baseline (1729.679 us; speedup 1.0000x reference)
//
#include <hip/hip_runtime.h>

#define T_ 1024
#define B_ 128
#define H_ 128
#define L_ 20
#define G4H_ 512
#define NCH 8              // batch chunks of 16 rows
#define RING 64            // ring depth (steps)
#define GRPSZ 2            // flag/publish granularity (steps)
#define FSTRIDE 32         // flag padding: 32 ints = 128 B
#define LEAD 12            // initial producer lead (steps) = slack seed

typedef _Float16 f16x8 __attribute__((ext_vector_type(8)));
typedef _Float16 f16x4 __attribute__((ext_vector_type(4)));
typedef float f32x4 __attribute__((ext_vector_type(4)));

__device__ __forceinline__ float fast_sig(float x) {
  float e = __builtin_amdgcn_exp2f(-1.44269504f * x);
  return __builtin_amdgcn_rcpf(1.0f + e);
}
__device__ __forceinline__ float fast_tanh(float x) {
  float e = __builtin_amdgcn_exp2f(2.88539008f * x);
  return 1.0f - 2.0f * __builtin_amdgcn_rcpf(e + 1.0f);
}

#define VMW(n) asm volatile("s_waitcnt vmcnt(" #n ")" ::: "memory")
#define LGKM0() asm volatile("s_waitcnt lgkmcnt(0)" ::: "memory")

// ---- device-scope (sc1) ops: serviced at LLC, no L2 wb/inv ----
__device__ __forceinline__ int flag_ld(const int* p) {  // blocking (rare path)
  int r;
  asm volatile("global_load_dword %0, %1, off sc1\n\ts_waitcnt vmcnt(0)"
               : "=v"(r) : "v"(p) : "memory");
  return r;
}
__device__ __forceinline__ void flag_issue(int* d, const int* p) {  // issue only
  asm volatile("global_load_dword %0, %1, off sc1" : "=&v"(*d) : "v"(p) : "memory");
}
__device__ __forceinline__ void flag_st(int* p, int v) {
  asm volatile("global_store_dword %0, %1, off sc1" :: "v"(p), "v"(v) : "memory");
}
__device__ __forceinline__ void xld_sc1(f16x4* d, const _Float16* p) {  // issue only
  asm volatile("global_load_dwordx2 %0, %1, off sc1" : "=&v"(*d) : "v"(p) : "memory");
}
__device__ __forceinline__ void xld_plain(f16x4* d, const _Float16* p) {
  asm volatile("global_load_dwordx2 %0, %1, off" : "=&v"(*d) : "v"(p) : "memory");
}
__device__ __forceinline__ void st8_sc1(_Float16* p, f16x4 v) {
  asm volatile("global_store_dwordx2 %0, %1, off sc1" :: "v"(p), "v"(v) : "memory");
}
__device__ __forceinline__ void st16_plain(float* p, f32x4 v) {
  asm volatile("global_store_dwordx4 %0, %1, off" :: "v"(p), "v"(v) : "memory");
}

__global__ void wconv_kernel(const float* __restrict__ Wih, const float* __restrict__ Whh,
                             _Float16* __restrict__ Wif, _Float16* __restrict__ Whf) {
  int i = blockIdx.x * 256 + threadIdx.x;
  if (i < L_ * G4H_ * H_) {
    Wif[i] = (_Float16)Wih[i];
    Whf[i] = (_Float16)Whh[i];
  }
}

__global__ void emb_kernel(const int* __restrict__ xids, const float* __restrict__ emb,
                           float* __restrict__ out_emb, _Float16* __restrict__ X0) {
  int row = blockIdx.x;
  int d = threadIdx.x;
  int tok = xids[row];
  float v = emb[(size_t)tok * H_ + d];
  out_emb[(size_t)row * H_ + d] = v;
  X0[(size_t)row * H_ + d] = (_Float16)v;
}

// R8: fragment-order LDS (conflict-free b128), per-step sc1 ring stores,
// fully counted vmcnt ledger (uniform across waves), flag prefetch + slack.
// Per-wave VM-op order per 2-step group (ledger):
//   boundary: flag_st | stepE: [h-st][fR][fC][x(t+4)] | stepO: [h-st][x(t+5)]
//   waits: C(even)=vmcnt(2), C(odd)=vmcnt(5), end-of-odd=vmcnt(1); tail(T-8)=0.
__launch_bounds__(512, 2)
__global__ void lstm_persist_kernel(const _Float16* __restrict__ Wif,
                                    const _Float16* __restrict__ Whf,
                                    const float* __restrict__ bih,
                                    const float* __restrict__ bhh,
                                    const _Float16* __restrict__ X0,
                                    _Float16* __restrict__ XR,
                                    float* __restrict__ out_h,
                                    int* __restrict__ rdy) {
  const int l = blockIdx.x >> 3;
  const int chunk = blockIdx.x & 7;
  const int tid = threadIdx.x;
  const int lane = tid & 63;
  const int wave = tid >> 6;
  const int lr = lane & 15;    // A row (hidden j) / B col (batch) / D col
  const int lhi = lane >> 4;   // k-subgroup; D row group
  const int ub = wave * 16;    // hidden slice base

  // ---- weight fragments (A-operand, verified R7): W[j=G*128+ub+lr][kt*32+lhi*8..+8]
  f16x8 wi[4][4], wh[4][4];
  f32x4 bias4[4];
  {
    const _Float16* wip = Wif + (size_t)l * G4H_ * H_;
    const _Float16* whp = Whf + (size_t)l * G4H_ * H_;
#pragma unroll
    for (int G = 0; G < 4; ++G) {
      int j = G * 128 + ub + lr;
#pragma unroll
      for (int kt = 0; kt < 4; ++kt) {
        wi[G][kt] = *(const f16x8*)(wip + (size_t)j * H_ + kt * 32 + lhi * 8);
        wh[G][kt] = *(const f16x8*)(whp + (size_t)j * H_ + kt * 32 + lhi * 8);
      }
      int jb = G * 128 + ub + lhi * 4;  // D row = jb + r
      bias4[G] = *(const f32x4*)&bih[l * G4H_ + jb];
      bias4[G] += *(const f32x4*)&bhh[l * G4H_ + jb];
    }
  }

  // ---- fragment-order LDS: elem idx = kt*512 + lane*8 (+0..7) ----
  __shared__ _Float16 xs[4][2048];  // x pipeline, 4 slots
  __shared__ _Float16 hs[2][2048];  // h exchange, ping-pong

  // coop x-stage mapping: thread tid owns dest f16 idx tid*4
  const int xb = (tid >> 1) & 15;                                      // batch
  const int xk = ((tid >> 7) << 5) | (((tid >> 5) & 3) << 3) | ((tid & 1) << 2);
  // h writer: produces h[b=lr][k=hk..hk+4)
  const int hk = ub + lhi * 4;
  const int hdst = ((hk >> 5) << 9) + (((((hk & 31) >> 3) << 4) + lr) << 3) + ((lhi & 1) << 2);

  const size_t tile16 = (size_t)16 * H_;  // 2048 f16 per step-slice
  const _Float16* ring_in =
      (l > 0) ? XR + (size_t)((l - 1) * NCH + chunk) * RING * tile16 : X0;
  _Float16* ring_out = XR + (size_t)(l * NCH + chunk) * RING * tile16;

  int* rout = rdy + (l * NCH + chunk) * FSTRIDE;
  const int* rin = (l > 0) ? rdy + ((l - 1) * NCH + chunk) * FSTRIDE : rout;
  const int* rcons = (l < L_ - 1) ? rdy + ((l + 1) * NCH + chunk) * FSTRIDE : rout;

  auto xgsrc = [&](int t) -> const _Float16* {
    return (l == 0) ? X0 + ((size_t)t * B_ + chunk * 16 + xb) * H_ + xk
                    : ring_in + (size_t)(t & (RING - 1)) * tile16 + xb * H_ + xk;
  };

  int rin_c = 0, rcons_c = 0;
  int fR = 0, fC = 0;  // async flag registers

  // ---------- prologue: lead gate, stage x0..x3, a0 = bias + Wih·x0 ----------
  if (l > 0) {
    while (rin_c < LEAD) { rin_c = flag_ld(rin); __builtin_amdgcn_s_sleep(2); }
  }
  {
    f16x4 v0, v1, v2, v3;
    if (l == 0) { xld_plain(&v0, xgsrc(0)); xld_plain(&v1, xgsrc(1));
                  xld_plain(&v2, xgsrc(2)); xld_plain(&v3, xgsrc(3)); }
    else        { xld_sc1(&v0, xgsrc(0)); xld_sc1(&v1, xgsrc(1));
                  xld_sc1(&v2, xgsrc(2)); xld_sc1(&v3, xgsrc(3)); }
    VMW(0);
    *(f16x4*)&xs[0][tid * 4] = v0;
    *(f16x4*)&xs[1][tid * 4] = v1;
    *(f16x4*)&xs[2][tid * 4] = v2;
    *(f16x4*)&xs[3][tid * 4] = v3;
  }
  LGKM0();
  __builtin_amdgcn_s_barrier();

  float cst[4] = {0.f, 0.f, 0.f, 0.f};
  f32x4 a0[4], a1[4];
  {
    f16x8 xf[4];
#pragma unroll
    for (int kt = 0; kt < 4; ++kt) xf[kt] = *(const f16x8*)&xs[0][kt * 512 + lane * 8];
#pragma unroll
    for (int G = 0; G < 4; ++G) a0[G] = bias4[G];
#pragma unroll
    for (int kt = 0; kt < 4; ++kt)
#pragma unroll
      for (int G = 0; G < 4; ++G)
        a0[G] = __builtin_amdgcn_mfma_f32_16x16x32_f16(wi[G][kt], xf[kt], a0[G], 0, 0, 0);
  }

  f16x4 xspE, xspO;  // in-flight x regs, parity

// One step. AC = bias+Wih·x_t (pre-filled); AN <- bias+Wih·x_{t+1}.
// CVM: literal vmcnt at C. ODD: 1 => end-of-step vmcnt(1) (group end).
#define STEP(t_, AC, AN, XSP, CVM, ODD)                                          \
  {                                                                              \
    const int t = (t_);                                                          \
    if (t > 0) { /* hidden GEMM */                                               \
      f16x8 hf[4];                                                               \
      _Pragma("unroll")                                                          \
      for (int kt = 0; kt < 4; ++kt)                                             \
        hf[kt] = *(const f16x8*)&hs[(t - 1) & 1][kt * 512 + lane * 8];           \
      _Pragma("unroll")                                                          \
      for (int kt = 0; kt < 4; ++kt)                                             \
        _Pragma("unroll")                                                        \
        for (int G = 0; G < 4; ++G)                                              \
          AC[G] = __builtin_amdgcn_mfma_f32_16x16x32_f16(wh[G][kt], hf[kt], AC[G], 0, 0, 0); \
    }                                                                            \
    if (t + 1 < T_) { /* next-step input GEMM */                                 \
      f16x8 xf[4];                                                               \
      _Pragma("unroll")                                                          \
      for (int kt = 0; kt < 4; ++kt)                                             \
        xf[kt] = *(const f16x8*)&xs[(t + 1) & 3][kt * 512 + lane * 8];           \
      _Pragma("unroll")                                                          \
      for (int G = 0; G < 4; ++G) AN[G] = bias4[G];                              \
      _Pragma("unroll")                                                          \
      for (int kt = 0; kt < 4; ++kt)                                             \
        _Pragma("unroll")                                                        \
        for (int G = 0; G < 4; ++G)                                              \
          AN[G] = __builtin_amdgcn_mfma_f32_16x16x32_f16(wi[G][kt], xf[kt], AN[G], 0, 0, 0); \
    }                                                                            \
    if (t >= 2 && t + 2 < T_) { /* C: land x(t+2) into LDS */                    \
      if (t >= T_ - 8) { VMW(0); } else { VMW(CVM); }                            \
      *(f16x4*)&xs[(t + 2) & 3][tid * 4] = XSP;                                  \
    }                                                                            \
    float hnew[4]; /* gates */                                                   \
    _Pragma("unroll")                                                            \
    for (int r = 0; r < 4; ++r) {                                                \
      float iv = fast_sig(AC[0][r]);                                             \
      float fv = fast_sig(AC[1][r]);                                             \
      float gv = fast_tanh(AC[2][r]);                                            \
      float ov = fast_sig(AC[3][r]);                                             \
      float c = fv * cst[r] + iv * gv;                                           \
      cst[r] = c;                                                                \
      hnew[r] = ov * fast_tanh(c);                                               \
    }                                                                            \
    if (l < L_ - 1) { /* E: per-step ring store (8B sc1) */                      \
      f16x4 hp;                                                                  \
      _Pragma("unroll")                                                          \
      for (int r = 0; r < 4; ++r) hp[r] = (_Float16)hnew[r];                     \
      st8_sc1(ring_out + (size_t)(t & (RING - 1)) * tile16 + lr * H_ + hk, hp);  \
      *(f16x4*)&hs[t & 1][hdst] = hp;                                            \
    } else { /* E: fp32 output (16B) */                                          \
      f32x4 ov4;                                                                 \
      _Pragma("unroll")                                                          \
      for (int r = 0; r < 4; ++r) ov4[r] = hnew[r];                              \
      st16_plain(out_h + ((size_t)t * B_ + chunk * 16 + lr) * H_ + hk, ov4);     \
      f16x4 hp;                                                                  \
      _Pragma("unroll")                                                          \
      for (int r = 0; r < 4; ++r) hp[r] = (_Float16)hnew[r];                     \
      *(f16x4*)&hs[t & 1][hdst] = hp;                                            \
    }                                                                            \
    if (!(ODD)) { /* F: prefetch flags (uniform op count for all l) */           \
      flag_issue(&fR, (int*)rin);                                                \
      flag_issue(&fC, (int*)rcons);                                              \
    }                                                                            \
    if (t + 4 < T_) { /* G: issue x(t+4) */                                      \
      if (l == 0) xld_plain(&XSP, xgsrc(t + 4)); else xld_sc1(&XSP, xgsrc(t + 4)); \
    }                                                                            \
    if (ODD) { if (t >= T_ - 8) { VMW(0); } else { VMW(1); } }                   \
    LGKM0();                                                                     \
    __builtin_amdgcn_s_barrier();                                                \
  }

  // ---------- main loop: 2 steps per group ----------
  for (int tg = 0; tg < T_; tg += GRPSZ) {
    if (tg > 0) {  // boundary (after end-of-odd vmcnt(1)+barrier)
      if (lane == 0) flag_st(rout, tg);  // every wave: uniform ledger
      rin_c = fR > rin_c ? fR : rin_c;
      rcons_c = fC > rcons_c ? fC : rcons_c;
      if (l > 0) {
        int need = tg + 3 * GRPSZ; if (need > T_) need = T_;
        while (rin_c < need) { rin_c = flag_ld(rin); __builtin_amdgcn_s_sleep(2); }
      }
      if (l < L_ - 1) {
        int need = tg + GRPSZ - RING + 8;
        if (need > 0)
          while (rcons_c < need) { rcons_c = flag_ld(rcons); __builtin_amdgcn_s_sleep(2); }
      }
    }
    STEP(tg, a0, a1, xspE, 2, 0)
    STEP(tg + 1, a1, a0, xspO, 5, 1)
  }

  // ---------- epilogue ----------
  __syncthreads();  // full vmcnt(0) drain: all ring/out stores at LLC
  if (tid == 0) flag_st(rout, T_);
}

extern "C" void kernel_launch(void* const* d_in, const int* in_sizes, int n_in,
                              void* d_out, int out_size, void* d_ws, size_t ws_size,
                              hipStream_t stream) {
  const int* xids = (const int*)d_in[0];
  const float* emb = (const float*)d_in[1];
  const float* Wih = (const float*)d_in[2];
  const float* Whh = (const float*)d_in[3];
  const float* bih = (const float*)d_in[4];
  const float* bhh = (const float*)d_in[5];
  float* out = (float*)d_out;
  float* out_h = out;                              // output 0: [T,B,H]
  float* out_emb = out + (size_t)T_ * B_ * H_;     // output 1: [T,B,H]

  char* ws = (char*)d_ws;
  const size_t RDY_BYTES = (size_t)L_ * NCH * FSTRIDE * 4;
  const size_t X0_BYTES = (size_t)T_ * B_ * H_ * 2;
  const size_t XR_BYTES = (size_t)L_ * NCH * RING * 16 * H_ * 2;
  const size_t WF_BYTES = (size_t)L_ * G4H_ * H_ * 2;
  int* rdyp = (int*)ws;
  _Float16* X0 = (_Float16*)(ws + RDY_BYTES);
  _Float16* XR = (_Float16*)(ws + RDY_BYTES + X0_BYTES);
  _Float16* Wif = (_Float16*)(ws + RDY_BYTES + X0_BYTES + XR_BYTES);
  _Float16* Whf = (_Float16*)(ws + RDY_BYTES + X0_BYTES + XR_BYTES + WF_BYTES);

  hipMemsetAsync(rdyp, 0, RDY_BYTES, stream);
  wconv_kernel<<<(L_ * G4H_ * H_ + 255) / 256, 256, 0, stream>>>(Wih, Whh, Wif, Whf);
  emb_kernel<<<T_ * B_, H_, 0, stream>>>(xids, emb, out_emb, X0);

  void* args[] = {(void*)&Wif, (void*)&Whf, (void*)&bih, (void*)&bhh,
                  (void*)&X0,  (void*)&XR,  (void*)&out_h, (void*)&rdyp};
  hipLaunchCooperativeKernel((void*)lstm_persist_kernel, dim3(L_ * NCH), dim3(512),
                             args, 0, stream);
}

// Round 9
// 1444.347 us; speedup vs baseline: 1.1976x; 1.1976x over previous
//
#include <hip/hip_runtime.h>

#define T_ 1024
#define B_ 128
#define H_ 128
#define L_ 20
#define G4H_ 512
#define NCH 8              // batch chunks of 16 rows
#define RING 64            // ring depth (steps)
#define GRP 4              // flag granularity (steps)
#define FSTRIDE 32         // flag padding: 32 ints = 128 B
#define LEAD 12            // initial producer lead (steps)

typedef _Float16 f16x8 __attribute__((ext_vector_type(8)));
typedef _Float16 f16x4 __attribute__((ext_vector_type(4)));
typedef float f32x4 __attribute__((ext_vector_type(4)));

__device__ __forceinline__ float fast_sig(float x) {
  float e = __builtin_amdgcn_exp2f(-1.44269504f * x);
  return __builtin_amdgcn_rcpf(1.0f + e);
}
__device__ __forceinline__ float fast_tanh(float x) {
  float e = __builtin_amdgcn_exp2f(2.88539008f * x);
  return 1.0f - 2.0f * __builtin_amdgcn_rcpf(e + 1.0f);
}

#define VMW(n) asm volatile("s_waitcnt vmcnt(" #n ")" ::: "memory")
#define LGKM0() asm volatile("s_waitcnt lgkmcnt(0)" ::: "memory")

// ---- device-scope (sc1) ops: serviced at LLC, no L2 wb/inv ----
__device__ __forceinline__ int flag_ld(const int* p) {  // blocking
  int r;
  asm volatile("global_load_dword %0, %1, off sc1\n\ts_waitcnt vmcnt(0)"
               : "=v"(r) : "v"(p) : "memory");
  return r;
}
__device__ __forceinline__ void flag_issue(int* d, const int* p) {  // issue only
  asm volatile("global_load_dword %0, %1, off sc1" : "=&v"(*d) : "v"(p) : "memory");
}
__device__ __forceinline__ void flag_st(int* p, int v) {
  asm volatile("global_store_dword %0, %1, off sc1" :: "v"(p), "v"(v) : "memory");
}
__device__ __forceinline__ void ld16_sc1(f16x8* d, const _Float16* p) {  // issue only
  asm volatile("global_load_dwordx4 %0, %1, off sc1" : "=&v"(*d) : "v"(p) : "memory");
}
__device__ __forceinline__ void ld16_plain(f16x8* d, const _Float16* p) {
  asm volatile("global_load_dwordx4 %0, %1, off" : "=&v"(*d) : "v"(p) : "memory");
}
__device__ __forceinline__ void st8_sc1(_Float16* p, f16x4 v) {
  asm volatile("global_store_dwordx2 %0, %1, off sc1" :: "v"(p), "v"(v) : "memory");
}
__device__ __forceinline__ void st16_plain(float* p, f32x4 v) {
  asm volatile("global_store_dwordx4 %0, %1, off" :: "v"(p), "v"(v) : "memory");
}

__global__ void wconv_kernel(const float* __restrict__ Wih, const float* __restrict__ Whh,
                             _Float16* __restrict__ Wif, _Float16* __restrict__ Whf) {
  int i = blockIdx.x * 256 + threadIdx.x;
  if (i < L_ * G4H_ * H_) {
    Wif[i] = (_Float16)Wih[i];
    Whf[i] = (_Float16)Whh[i];
  }
}

// Embedding: fp32 row-major copy to d_out + fp16 FRAGMENT-ORDER copy to X0.
// Fragment index of element (b,k) within a 16x128 tile:
//   FIDX(b,k) = (k>>5)*512 + (((k>>3)&3)*16 + b)*8 + (k&7)
__global__ void emb_kernel(const int* __restrict__ xids, const float* __restrict__ emb,
                           float* __restrict__ out_emb, _Float16* __restrict__ X0) {
  int row = blockIdx.x;        // t*B + b
  int d = threadIdx.x;         // 0..127 (k)
  int t = row >> 7, b = row & 127;
  int tok = xids[row];
  float v = emb[(size_t)tok * H_ + d];
  out_emb[(size_t)row * H_ + d] = v;
  int fidx = ((d >> 5) << 9) | (((((d >> 3) & 3) << 4) | (b & 15)) << 3) | (d & 7);
  X0[((size_t)t * NCH + (b >> 4)) * 2048 + fidx] = (_Float16)v;
}

// R9: ring in fragment order. x: direct global->VGPR fragment loads (no LDS).
// h: fragment-order LDS exchange (conflict-free, R8-verified) + one coalesced
// 8B sc1 ring store per lane per step. Counted-vmcnt ledger per wave per step:
//   [VMW(N) xf-wait][16+16 MFMA][issue 4 x-loads][gates][1 ring/out store]
// Boundary per GRP=4: VMW(0)+barrier -> flag_st -> gate(cached flags) ->
// flag_issue x2 (drained by next boundary's VMW(0); consumed after it).
__launch_bounds__(512, 2)
__global__ void lstm_persist_kernel(const _Float16* __restrict__ Wif,
                                    const _Float16* __restrict__ Whf,
                                    const float* __restrict__ bih,
                                    const float* __restrict__ bhh,
                                    const _Float16* __restrict__ X0,
                                    _Float16* __restrict__ XR,
                                    float* __restrict__ out_h,
                                    int* __restrict__ rdy) {
  const int l = blockIdx.x >> 3;
  const int chunk = blockIdx.x & 7;
  const int tid = threadIdx.x;
  const int lane = tid & 63;
  const int wave = tid >> 6;
  const int lr = lane & 15;    // A row (hidden j) / B col (batch) / D col
  const int lhi = lane >> 4;   // k-subgroup; D row group
  const int ub = wave * 16;
  const int hk = ub + lhi * 4; // this lane's 4 produced hidden k's
  const int hdst = ((hk >> 5) << 9) + (((((hk >> 3) & 3) << 4) + lr) << 3) + ((lhi & 1) << 2);

  // ---- weight fragments (A-operand, R7-verified): W[j=G*128+ub+lr][kt*32+lhi*8..+8]
  f16x8 wi[4][4], wh[4][4];
  f32x4 bias4[4];
  {
    const _Float16* wip = Wif + (size_t)l * G4H_ * H_;
    const _Float16* whp = Whf + (size_t)l * G4H_ * H_;
#pragma unroll
    for (int G = 0; G < 4; ++G) {
      int j = G * 128 + ub + lr;
#pragma unroll
      for (int kt = 0; kt < 4; ++kt) {
        wi[G][kt] = *(const f16x8*)(wip + (size_t)j * H_ + kt * 32 + lhi * 8);
        wh[G][kt] = *(const f16x8*)(whp + (size_t)j * H_ + kt * 32 + lhi * 8);
      }
      int jb = G * 128 + ub + lhi * 4;
      bias4[G] = *(const f32x4*)&bih[l * G4H_ + jb];
      bias4[G] += *(const f32x4*)&bhh[l * G4H_ + jb];
    }
  }

  __shared__ __align__(16) _Float16 hs[2][2048];  // fragment-order h exchange

  const _Float16* ring_in =
      (l > 0) ? XR + (size_t)((l - 1) * NCH + chunk) * (RING * 2048) : (const _Float16*)0;
  _Float16* ring_out = XR + (size_t)(l * NCH + chunk) * (RING * 2048);

  int* rout = rdy + (l * NCH + chunk) * FSTRIDE;
  const int* rin = (l > 0) ? rdy + ((l - 1) * NCH + chunk) * FSTRIDE : rout;
  const int* rcons = (l < L_ - 1) ? rdy + ((l + 1) * NCH + chunk) * FSTRIDE : rout;

  f16x8 xf[4];       // x fragments, single logical buffer (compiler may dbuf)
  int fR = 0, fC = 0;

#define XISSUE(t_) {                                                              \
    if (l == 0) {                                                                 \
      const _Float16* bp = X0 + ((size_t)(t_) * NCH + chunk) * 2048 + lane * 8;   \
      ld16_plain(&xf[0], bp);       ld16_plain(&xf[1], bp + 512);                 \
      ld16_plain(&xf[2], bp + 1024); ld16_plain(&xf[3], bp + 1536);               \
    } else {                                                                      \
      const _Float16* bp = ring_in + (size_t)((t_) & (RING - 1)) * 2048 + lane * 8; \
      ld16_sc1(&xf[0], bp);       ld16_sc1(&xf[1], bp + 512);                     \
      ld16_sc1(&xf[2], bp + 1024); ld16_sc1(&xf[3], bp + 1536);                   \
    } }

  // ---------- prologue ----------
  if (l > 0) {
    int v = 0;
    while ((v = flag_ld(rin)) < LEAD) __builtin_amdgcn_s_sleep(2);
    fR = v;
  }
  float cst[4] = {0.f, 0.f, 0.f, 0.f};
  f32x4 a0[4], a1[4];
  XISSUE(0);
  VMW(0);
  __builtin_amdgcn_sched_barrier(0);
#pragma unroll
  for (int G = 0; G < 4; ++G) a0[G] = bias4[G];
#pragma unroll
  for (int kt = 0; kt < 4; ++kt)
#pragma unroll
    for (int G = 0; G < 4; ++G)
      a0[G] = __builtin_amdgcn_mfma_f32_16x16x32_f16(wi[G][kt], xf[kt], a0[G], 0, 0, 0);
  XISSUE(1);                      // 4 loads in flight
  flag_issue(&fR, rin);           // +2 flag loads (newest)
  flag_issue(&fC, rcons);

// One step. AC = bias+Wih·x_t (pre-filled); AN <- bias+Wih·x_{t+1} from xf.
// VMN: counted wait so the 4 xf loads (oldest outstanding) are complete.
#define STEP(t_, AC, AN, VMN) {                                                   \
    const int t = (t_);                                                           \
    if (t > 0) { /* hidden GEMM from LDS (compiler inserts lgkm waits) */         \
      f16x8 hf0 = *(const f16x8*)&hs[(t - 1) & 1][lane * 8];                      \
      f16x8 hf1 = *(const f16x8*)&hs[(t - 1) & 1][512 + lane * 8];                \
      f16x8 hf2 = *(const f16x8*)&hs[(t - 1) & 1][1024 + lane * 8];               \
      f16x8 hf3 = *(const f16x8*)&hs[(t - 1) & 1][1536 + lane * 8];               \
      _Pragma("unroll")                                                           \
      for (int G = 0; G < 4; ++G) {                                               \
        AC[G] = __builtin_amdgcn_mfma_f32_16x16x32_f16(wh[G][0], hf0, AC[G], 0, 0, 0); \
        AC[G] = __builtin_amdgcn_mfma_f32_16x16x32_f16(wh[G][1], hf1, AC[G], 0, 0, 0); \
        AC[G] = __builtin_amdgcn_mfma_f32_16x16x32_f16(wh[G][2], hf2, AC[G], 0, 0, 0); \
        AC[G] = __builtin_amdgcn_mfma_f32_16x16x32_f16(wh[G][3], hf3, AC[G], 0, 0, 0); \
      }                                                                           \
    }                                                                             \
    if (t + 1 < T_) { /* input GEMM for t+1 from xf regs */                       \
      VMW(VMN);                                                                   \
      __builtin_amdgcn_sched_barrier(0);                                          \
      _Pragma("unroll")                                                           \
      for (int G = 0; G < 4; ++G) AN[G] = bias4[G];                               \
      _Pragma("unroll")                                                           \
      for (int kt = 0; kt < 4; ++kt)                                              \
        _Pragma("unroll")                                                         \
        for (int G = 0; G < 4; ++G)                                               \
          AN[G] = __builtin_amdgcn_mfma_f32_16x16x32_f16(wi[G][kt], xf[kt], AN[G], 0, 0, 0); \
    }                                                                             \
    if (t + 2 < T_) XISSUE(t + 2); /* 4 loads (WAR on xf keeps order) */          \
    float hnew[4];                                                                \
    _Pragma("unroll")                                                             \
    for (int r = 0; r < 4; ++r) {                                                 \
      float iv = fast_sig(AC[0][r]);                                              \
      float fv = fast_sig(AC[1][r]);                                              \
      float gv = fast_tanh(AC[2][r]);                                             \
      float ov = fast_sig(AC[3][r]);                                              \
      float c = fv * cst[r] + iv * gv;                                            \
      cst[r] = c;                                                                 \
      hnew[r] = ov * fast_tanh(c);                                                \
    }                                                                             \
    f16x4 hp;                                                                     \
    _Pragma("unroll")                                                             \
    for (int r = 0; r < 4; ++r) hp[r] = (_Float16)hnew[r];                        \
    if (l < L_ - 1) { /* coalesced fragment-order ring store, 8B/lane */          \
      st8_sc1(ring_out + (size_t)(t & (RING - 1)) * 2048 + hdst, hp);             \
    } else { /* fp32 output, row-major */                                         \
      f32x4 ov4;                                                                  \
      _Pragma("unroll")                                                           \
      for (int r = 0; r < 4; ++r) ov4[r] = hnew[r];                               \
      st16_plain(out_h + ((size_t)t * B_ + chunk * 16 + lr) * H_ + hk, ov4);      \
    }                                                                             \
    *(f16x4*)&hs[t & 1][hdst] = hp;                                               \
    LGKM0();                                                                      \
    __builtin_amdgcn_s_barrier();                                                 \
    asm volatile("" ::: "memory");                                                \
  }

  // ---------- group 0 ----------
  STEP(0, a0, a1, 2)   // leaves the 2 prologue flag loads outstanding
  STEP(1, a1, a0, 1)
  STEP(2, a0, a1, 1)
  STEP(3, a1, a0, 1)

  // ---------- main groups ----------
  for (int tg = GRP; tg < T_; tg += GRP) {
    VMW(0);                          // drain: ring stores, x loads, flag loads
    __builtin_amdgcn_s_barrier();    // all waves drained
    asm volatile("" ::: "memory");
    if (tid == 0) flag_st(rout, tg); // certify steps < tg
    if (l > 0) {                     // license x(tg+2..tg+5) direct loads
      int need = tg + GRP + 2; if (need > T_) need = T_;
      while (fR < need) { fR = flag_ld(rin); __builtin_amdgcn_s_sleep(2); }
    }
    if (l < L_ - 1) {                // ring slot-reuse backpressure
      int need = tg - 52;
      if (need > 0)
        while (fC < need) { fC = flag_ld(rcons); __builtin_amdgcn_s_sleep(2); }
    }
    flag_issue(&fR, rin);            // for NEXT boundary (drained by its VMW(0))
    flag_issue(&fC, rcons);
    STEP(tg, a0, a1, 3)              // no xf wait needed (boundary drained)
    STEP(tg + 1, a1, a0, 1)
    STEP(tg + 2, a0, a1, 1)
    STEP(tg + 3, a1, a0, 1)
  }

  // ---------- epilogue ----------
  __syncthreads();                   // full drain: last stores at LLC
  if (tid == 0) flag_st(rout, T_);
}

extern "C" void kernel_launch(void* const* d_in, const int* in_sizes, int n_in,
                              void* d_out, int out_size, void* d_ws, size_t ws_size,
                              hipStream_t stream) {
  const int* xids = (const int*)d_in[0];
  const float* emb = (const float*)d_in[1];
  const float* Wih = (const float*)d_in[2];
  const float* Whh = (const float*)d_in[3];
  const float* bih = (const float*)d_in[4];
  const float* bhh = (const float*)d_in[5];
  float* out = (float*)d_out;
  float* out_h = out;                              // output 0: [T,B,H]
  float* out_emb = out + (size_t)T_ * B_ * H_;     // output 1: [T,B,H]

  char* ws = (char*)d_ws;
  const size_t RDY_BYTES = (size_t)L_ * NCH * FSTRIDE * 4;
  const size_t X0_BYTES = (size_t)T_ * B_ * H_ * 2;
  const size_t XR_BYTES = (size_t)L_ * NCH * RING * 2048 * 2;
  const size_t WF_BYTES = (size_t)L_ * G4H_ * H_ * 2;
  int* rdyp = (int*)ws;
  _Float16* X0 = (_Float16*)(ws + RDY_BYTES);
  _Float16* XR = (_Float16*)(ws + RDY_BYTES + X0_BYTES);
  _Float16* Wif = (_Float16*)(ws + RDY_BYTES + X0_BYTES + XR_BYTES);
  _Float16* Whf = (_Float16*)(ws + RDY_BYTES + X0_BYTES + XR_BYTES + WF_BYTES);

  hipMemsetAsync(rdyp, 0, RDY_BYTES, stream);
  wconv_kernel<<<(L_ * G4H_ * H_ + 255) / 256, 256, 0, stream>>>(Wih, Whh, Wif, Whf);
  emb_kernel<<<T_ * B_, H_, 0, stream>>>(xids, emb, out_emb, X0);

  void* args[] = {(void*)&Wif, (void*)&Whf, (void*)&bih, (void*)&bhh,
                  (void*)&X0,  (void*)&XR,  (void*)&out_h, (void*)&rdyp};
  hipLaunchCooperativeKernel((void*)lstm_persist_kernel, dim3(L_ * NCH), dim3(512),
                             args, 0, stream);
}